// Round 1
// baseline (155.663 us; speedup 1.0000x reference)
//
#include <hip/hip_runtime.h>
#include <math.h>

#define NN 4096
#define NCELLS ((size_t)NN * (size_t)NN)
#define ROWS_PER_BLOCK 16

// mysign(|v|) - 0.5, computed exactly like the reference:
// e = exp(6*|v|); ((e-1)/(e+1)+1)/2 - 0.5 = 0.5*(e-1)/(e+1)
// (for e=inf this yields NaN, matching jnp semantics)
__device__ __forceinline__ float smh(float v) {
    float e = expf(6.0f * fabsf(v));
    return 0.5f * (e - 1.0f) / (e + 1.0f);
}

__global__ __launch_bounds__(256) void scatter_edges_k(
    const int* __restrict__ edges, const float* __restrict__ weights,
    const float* __restrict__ stat, float* Am, float* Wm, int E) {
    int e = blockIdx.x * 256 + threadIdx.x;
    if (e < E) {
        int r = edges[2 * e];
        int c = edges[2 * e + 1];
        size_t idx = (size_t)r * NN + c;
        atomicAdd(&Wm[idx], weights[e]);
        atomicAdd(&Am[idx], stat[e]);
    }
}

__global__ __launch_bounds__(256) void scatter_c_k(
    const int* __restrict__ edges_c, const float* __restrict__ grdt,
    float* Bm, int EC) {
    int e = blockIdx.x * 256 + threadIdx.x;
    if (e < EC) {
        int r = edges_c[2 * e];
        int c = edges_c[2 * e + 1];
        size_t idx = (size_t)r * NN + c;
        atomicAdd(&Bm[idx], grdt[e]);
    }
}

// Pass 1: v = B*(A-1) + A*W per cell; write V over A; accumulate per-column
// g[c] (sum of v) and nin_d[c] (sum of mysign(|v|)-0.5) in registers, one
// atomicAdd per (block, column) at the end.
// grid: x = 4 column tiles (256 threads * 4 cols), y = 4096/ROWS_PER_BLOCK strips
__global__ __launch_bounds__(256) void pass1_k(
    float* AV, const float* __restrict__ Wm, const float* __restrict__ Bm,
    float* __restrict__ g_col, float* __restrict__ nin_d) {
    const int c0 = (blockIdx.x * 256 + threadIdx.x) * 4;
    const int r0 = blockIdx.y * ROWS_PER_BLOCK;
    float gc0 = 0.f, gc1 = 0.f, gc2 = 0.f, gc3 = 0.f;
    float nd0 = 0.f, nd1 = 0.f, nd2 = 0.f, nd3 = 0.f;
    for (int r = 0; r < ROWS_PER_BLOCK; ++r) {
        size_t idx = (size_t)(r0 + r) * NN + (size_t)c0;
        float4 a = *(const float4*)(AV + idx);
        float4 w = *(const float4*)(Wm + idx);
        float4 b = *(const float4*)(Bm + idx);
        float4 v;
        v.x = b.x * (a.x - 1.0f) + a.x * w.x;
        v.y = b.y * (a.y - 1.0f) + a.y * w.y;
        v.z = b.z * (a.z - 1.0f) + a.z * w.z;
        v.w = b.w * (a.w - 1.0f) + a.w * w.w;
        *(float4*)(AV + idx) = v;
        gc0 += v.x; nd0 += smh(v.x);
        gc1 += v.y; nd1 += smh(v.y);
        gc2 += v.z; nd2 += smh(v.z);
        gc3 += v.w; nd3 += smh(v.w);
    }
    atomicAdd(&g_col[c0 + 0], gc0);
    atomicAdd(&g_col[c0 + 1], gc1);
    atomicAdd(&g_col[c0 + 2], gc2);
    atomicAdd(&g_col[c0 + 3], gc3);
    atomicAdd(&nin_d[c0 + 0], nd0);
    atomicAdd(&nin_d[c0 + 1], nd1);
    atomicAdd(&nin_d[c0 + 2], nd2);
    atomicAdd(&nin_d[c0 + 3], nd3);
}

// good[c] = N_in != 0 ? clip(g/N_in, -1, 1) : 1   (NaN-propagating clip)
__global__ __launch_bounds__(256) void good_k(
    const float* __restrict__ g_col, const float* __restrict__ nin_d,
    float* __restrict__ good_buf, float* __restrict__ good_out) {
    int c = blockIdx.x * 256 + threadIdx.x;
    float Nin = 2048.0f + nin_d[c];   // 0.5 * 4096 zero-entries baseline
    float gd = 1.0f;
    if (Nin != 0.0f) {
        float x = g_col[c] / Nin;
        gd = x < -1.0f ? -1.0f : (x > 1.0f ? 1.0f : x);  // NaN stays NaN
    }
    good_buf[c] = gd;
    good_out[c] = gd;
}

// Pass 2: one block per row. N_out row sum of (mysign-0.5); f row sum of
// contrib over v != 0; fair = clip(f/N_out, 0, 1).
__global__ __launch_bounds__(256) void pass2_k(
    const float* __restrict__ V, const float* __restrict__ good_buf,
    float* __restrict__ fair_out) {
    const int r = blockIdx.x;
    const int tid = threadIdx.x;
    float nd = 0.f, fs = 0.f;
    const float* vrow = V + (size_t)r * NN;
#pragma unroll
    for (int it = 0; it < 4; ++it) {
        int c = (it * 256 + tid) * 4;
        float4 v = *(const float4*)(vrow + c);
        float4 gd = *(const float4*)(good_buf + c);
        nd += smh(v.x);
        if (v.x != 0.0f) fs += 1.0f - 0.5f * fabsf(v.x - gd.x);
        nd += smh(v.y);
        if (v.y != 0.0f) fs += 1.0f - 0.5f * fabsf(v.y - gd.y);
        nd += smh(v.z);
        if (v.z != 0.0f) fs += 1.0f - 0.5f * fabsf(v.z - gd.z);
        nd += smh(v.w);
        if (v.w != 0.0f) fs += 1.0f - 0.5f * fabsf(v.w - gd.w);
    }
    __shared__ float lds[8];
    for (int off = 32; off > 0; off >>= 1) {
        nd += __shfl_down(nd, off, 64);
        fs += __shfl_down(fs, off, 64);
    }
    int lane = tid & 63, wv = tid >> 6;
    if (lane == 0) { lds[wv] = nd; lds[4 + wv] = fs; }
    __syncthreads();
    if (tid == 0) {
        float Nout = 2048.0f + (lds[0] + lds[1] + lds[2] + lds[3]);
        float f = lds[4] + lds[5] + lds[6] + lds[7];
        float fair = 1.0f;
        if (Nout != 0.0f) {
            float x = f / Nout;
            fair = x < 0.0f ? 0.0f : (x > 1.0f ? 1.0f : x);  // NaN stays NaN
        }
        fair_out[r] = fair;
    }
}

__global__ __launch_bounds__(512) void gsum_k(
    const float* __restrict__ good_buf, const int* __restrict__ targets,
    int T, float* __restrict__ out0) {
    int t = threadIdx.x;
    float s = 0.f;
    for (int i = t; i < T; i += 512) {
        float gt = good_buf[targets[i]];
        s += (gt == gt) ? gt : 0.0f;   // NaN -> 0
    }
    for (int off = 32; off > 0; off >>= 1) s += __shfl_down(s, off, 64);
    __shared__ float lds[8];
    int lane = t & 63, wv = t >> 6;
    if (lane == 0) lds[wv] = s;
    __syncthreads();
    if (t == 0) {
        float tot = 0.f;
        for (int i = 0; i < 8; ++i) tot += lds[i];
        out0[0] = tot;
    }
}

extern "C" void kernel_launch(void* const* d_in, const int* in_sizes, int n_in,
                              void* d_out, int out_size, void* d_ws, size_t ws_size,
                              hipStream_t stream) {
    const int*   edges   = (const int*)d_in[0];
    const float* weights = (const float*)d_in[1];
    const float* stat    = (const float*)d_in[2];
    const int*   edges_c = (const int*)d_in[3];
    const float* grdt    = (const float*)d_in[4];
    const int*   targets = (const int*)d_in[5];
    const int E  = in_sizes[1];
    const int EC = in_sizes[4];
    const int T  = in_sizes[5];
    float* out = (float*)d_out;

    float* AV       = (float*)d_ws;          // A, then V in-place  (NCELLS)
    float* Wm       = AV + NCELLS;           // NCELLS
    float* Bm       = Wm + NCELLS;           // NCELLS
    float* g_col    = Bm + NCELLS;           // NN
    float* nin_d    = g_col + NN;            // NN
    float* good_buf = nin_d + NN;            // NN

    // zero A, W, B and the column accumulators
    size_t zero_bytes = (3 * NCELLS + 2 * (size_t)NN) * sizeof(float);
    hipMemsetAsync(d_ws, 0, zero_bytes, stream);

    scatter_edges_k<<<(E + 255) / 256, 256, 0, stream>>>(edges, weights, stat, AV, Wm, E);
    scatter_c_k<<<(EC + 255) / 256, 256, 0, stream>>>(edges_c, grdt, Bm, EC);

    dim3 g1(4, NN / ROWS_PER_BLOCK);
    pass1_k<<<g1, 256, 0, stream>>>(AV, Wm, Bm, g_col, nin_d);

    good_k<<<NN / 256, 256, 0, stream>>>(g_col, nin_d, good_buf, out + 1 + NN);
    pass2_k<<<NN, 256, 0, stream>>>(AV, good_buf, out + 1);
    gsum_k<<<1, 512, 0, stream>>>(good_buf, targets, T, out);
}